// Round 14
// baseline (383.182 us; speedup 1.0000x reference)
//
#include <hip/hip_runtime.h>

typedef __attribute__((ext_vector_type(8))) short bf16x8;
typedef __attribute__((ext_vector_type(4))) float f32x4;
typedef __attribute__((ext_vector_type(4))) unsigned short us4;
typedef __attribute__((ext_vector_type(8))) unsigned short us8;

#define NROWS 262144
#define KC 256
#define DD 256
#define BM 128       // rows per block (8 steps x 16 rows)
#define DK 32        // D-chunk (= one MFMA K)
#define TAU 1.5e-3f  // flag threshold: ~9 sigma of single-pass bf16 error + np fp32 rounding
#define FCAP 65536   // flag list capacity

// ===== bit-exact numpy emulation helpers (defeat -ffp-contract) =====
__device__ __forceinline__ float np_pw128_sq(const float* a) {
    float r[8];
#pragma unroll
    for (int j = 0; j < 8; ++j) r[j] = __fmul_rn(a[j], a[j]);
    for (int i = 8; i < 128; i += 8) {
#pragma unroll
        for (int j = 0; j < 8; ++j)
            r[j] = __fadd_rn(r[j], __fmul_rn(a[i + j], a[i + j]));
    }
    float t01 = __fadd_rn(r[0], r[1]), t23 = __fadd_rn(r[2], r[3]);
    float t45 = __fadd_rn(r[4], r[5]), t67 = __fadd_rn(r[6], r[7]);
    return __fadd_rn(__fadd_rn(t01, t23), __fadd_rn(t45, t67));
}
__device__ __forceinline__ float np_sum256_sq(const float* a) {
    return __fadd_rn(np_pw128_sq(a), np_pw128_sq(a + 128));
}

// bf16 round-to-nearest-even
__device__ __forceinline__ unsigned short bf16_rne(float x) {
    unsigned b = __float_as_uint(x);
    b += 0x7FFFu + ((b >> 16) & 1u);
    return (unsigned short)(b >> 16);
}

// ---------- prep: se[k] = np-bit-exact sum(emb[k]^2); zero accum + flag count ----------
__global__ void vq_prep(const float* __restrict__ emb, float* __restrict__ se,
                        double* __restrict__ accum, int* __restrict__ gcnt) {
    int k = threadIdx.x;
    if (k == 0) { *accum = 0.0; *gcnt = 0; }
    se[k] = np_sum256_sq(emb + (size_t)k * DD);
}

// ---------- split emb -> dc-tiled bf16 (RNE) plane: plane[tile][k][32] ----------
__global__ void vq_split(const float* __restrict__ emb, unsigned short* __restrict__ ph) {
    int f = (blockIdx.x * 256 + threadIdx.x) * 4;   // element index
    float4 v = *reinterpret_cast<const float4*>(emb + f);
    int k = f >> 8, d = f & 255;
    int off = (d >> 5) * (KC * DK) + k * DK + (d & 31);
    us4 h;
    h[0] = bf16_rne(v.x); h[1] = bf16_rne(v.y);
    h[2] = bf16_rne(v.z); h[3] = bf16_rne(v.w);
    *reinterpret_cast<us4*>(ph + off) = h;
}

// ---------- main: persistent-B argmin, BARRIER-FREE K-loop, deferred merge ----------
__global__ __launch_bounds__(256, 2)
void vq_main(const float* __restrict__ ze, const unsigned short* __restrict__ ph,
             const float* __restrict__ se_g, float* __restrict__ out_inds,
             double* __restrict__ accum, int* __restrict__ glist, int* __restrict__ gcnt)
{
    __shared__ float se_s[KC];
    __shared__ float wv1[4 * BM], wv2[4 * BM];   // per-wave slices, no in-loop sync
    __shared__ int   wk1[4 * BM];
    __shared__ float red[256];

    const int t = threadIdx.x;
    const int w = t >> 6;          // wave: codes [64w, 64w+64)
    const int q = (t >> 4) & 3;    // k-quad within frag
    const int c = t & 15;          // A-row / B-col within frag
    const size_t m0 = (size_t)blockIdx.x * BM;

    se_s[t] = se_g[t];

    // ---- persistent B-frags: wave's 64 codes x 256 d, loaded once (L2-hot plane) ----
    bf16x8 bfr[4][8];   // [nf][dci]
#pragma unroll
    for (int nf = 0; nf < 4; ++nf)
#pragma unroll
        for (int dci = 0; dci < 8; ++dci)
            bfr[nf][dci] = *reinterpret_cast<const bf16x8*>(
                ph + dci * (KC * DK) + (w * 64 + nf * 16 + c) * DK + q * 8);

    __syncthreads();   // se_s visible (only barrier before the loop)

    // hoist this thread's 4 se values into registers (constant across steps/j)
    float se_v[4];
#pragma unroll
    for (int nf = 0; nf < 4; ++nf) se_v[nf] = se_s[64 * w + 16 * nf + c];

    float sz_run = 0.f;

    // ---- prologue: z loads for step 0 (lane (c,q): row c, d-slice q*8 of each dci) ----
    float4 z0[8], z1[8];
    {
        const float* zb = ze + (m0 + c) * DD + q * 8;
#pragma unroll
        for (int dci = 0; dci < 8; ++dci) {
            z0[dci] = *reinterpret_cast<const float4*>(zb + dci * 32);
            z1[dci] = *reinterpret_cast<const float4*>(zb + dci * 32 + 4);
        }
    }

    for (int step = 0; step < BM / 16; ++step) {
        // ---- 1) cvt z -> afrag (frees z regs); sz on wave 0 only ----
        bf16x8 afrag[8];
#pragma unroll
        for (int dci = 0; dci < 8; ++dci) {
            float4 a = z0[dci], b = z1[dci];
            if (w == 0) {
                sz_run = fmaf(a.x, a.x, sz_run); sz_run = fmaf(a.y, a.y, sz_run);
                sz_run = fmaf(a.z, a.z, sz_run); sz_run = fmaf(a.w, a.w, sz_run);
                sz_run = fmaf(b.x, b.x, sz_run); sz_run = fmaf(b.y, b.y, sz_run);
                sz_run = fmaf(b.z, b.z, sz_run); sz_run = fmaf(b.w, b.w, sz_run);
            }
            us8 h;
            h[0] = bf16_rne(a.x); h[1] = bf16_rne(a.y); h[2] = bf16_rne(a.z); h[3] = bf16_rne(a.w);
            h[4] = bf16_rne(b.x); h[5] = bf16_rne(b.y); h[6] = bf16_rne(b.z); h[7] = bf16_rne(b.w);
            afrag[dci] = __builtin_bit_cast(bf16x8, h);
        }
        // ---- 2) issue next step's z loads NOW; no barrier ahead -> latency hides under 3)+4) ----
        if (step < BM / 16 - 1) {
            const float* zb = ze + (m0 + (step + 1) * 16 + c) * DD + q * 8;
#pragma unroll
            for (int dci = 0; dci < 8; ++dci) {
                z0[dci] = *reinterpret_cast<const float4*>(zb + dci * 32);
                z1[dci] = *reinterpret_cast<const float4*>(zb + dci * 32 + 4);
            }
        }
        // ---- 3) MFMA: 4 nf x 8 dci ----
        f32x4 acc[4];
#pragma unroll
        for (int nf = 0; nf < 4; ++nf) acc[nf] = (f32x4){0.f, 0.f, 0.f, 0.f};
#pragma unroll
        for (int dci = 0; dci < 8; ++dci)
#pragma unroll
            for (int nf = 0; nf < 4; ++nf)
                acc[nf] = __builtin_amdgcn_mfma_f32_16x16x32_bf16(afrag[dci], bfr[nf][dci], acc[nf], 0, 0, 0);

        // ---- 4) wave-local argmin over 64 codes; write private LDS slice (no sync) ----
#pragma unroll
        for (int j = 0; j < 4; ++j) {
            float v1 = 3.4e38f, v2 = 3.4e38f; int k1 = 0x7fffffff;
#pragma unroll
            for (int nf = 0; nf < 4; ++nf) {
                int k = 64 * w + 16 * nf + c;
                float dv = fmaf(-2.f, acc[nf][j], se_v[nf]);
                if (dv < v1) { v2 = v1; v1 = dv; k1 = k; }
                else if (dv < v2) { v2 = dv; }
            }
#pragma unroll
            for (int off = 1; off < 16; off <<= 1) {
                float ov1 = __shfl_xor(v1, off, 64);
                float ov2 = __shfl_xor(v2, off, 64);
                int   ok1 = __shfl_xor(k1, off, 64);
                bool other = (ov1 < v1) || (ov1 == v1 && ok1 < k1);
                float nv2 = other ? fminf(v1, ov2) : fminf(v2, ov1);
                if (other) { v1 = ov1; k1 = ok1; }
                v2 = nv2;
            }
            if (c == 0) {
                int row = step * 16 + 4 * q + j;
                wv1[w * BM + row] = v1;
                wv2[w * BM + row] = v2;
                wk1[w * BM + row] = k1;
            }
        }
    }
    __syncthreads();   // single post-loop barrier: all wv slices visible

    // ---- final merge: thread t (t<128) merges 4 slices for row t ----
    float lossv = 0.f;
    if (t < BM) {
        float v1 = wv1[t], v2 = wv2[t]; int k1 = wk1[t];
#pragma unroll
        for (int ww = 1; ww < 4; ++ww) {
            float ov1 = wv1[ww * BM + t], ov2 = wv2[ww * BM + t];
            int ok1 = wk1[ww * BM + t];
            bool other = (ov1 < v1) || (ov1 == v1 && ok1 < k1);
            float nv2 = other ? fminf(v1, ov2) : fminf(v2, ov1);
            if (other) { v1 = ov1; k1 = ok1; }
            v2 = nv2;
        }
        out_inds[m0 + t] = (float)k1;
        lossv = v1;
        if (v2 - v1 < TAU) {
            int s_ = atomicAdd(gcnt, 1);
            if (s_ < FCAP) glist[s_] = (int)(m0 + t);
        }
    }
    __syncthreads();

    // ---- loss partial: sz (wave-0 lanes) + merged min-dists (t<128) ----
    red[t] = (w == 0 ? sz_run : 0.f) + (t < BM ? lossv : 0.f);
    __syncthreads();
    for (int s = 128; s > 0; s >>= 1) {
        if (t < s) red[t] += red[t + s];
        __syncthreads();
    }
    if (t == 0) atomicAdd(accum, (double)red[0]);
}

// ---------- deferred fix: bit-exact np fp32 pipeline, BATCHED 16 rows/group (r8-proven, inds only) ----------
__global__ __launch_bounds__(256)
void vq_fix(const float* __restrict__ ze, const float* __restrict__ emb,
            const float* __restrict__ se_g, const int* __restrict__ glist,
            const int* __restrict__ gcnt, float* __restrict__ out_inds)
{
    __shared__ float dq[16][256];
    __shared__ float srow_s[16];
    __shared__ int   rowid_s[16];

    const int t = threadIdx.x;
    int F = *gcnt; if (F > FCAP) F = FCAP;
    const float se_k = se_g[t];
    const float4* e4p = reinterpret_cast<const float4*>(emb + (size_t)t * DD);

    for (int g = blockIdx.x * 16; g < F; g += gridDim.x * 16) {
        __syncthreads();   // protect LDS reuse across iterations
        if (t < 16) {
            int idx = g + t; if (idx > F - 1) idx = F - 1;   // pad tail with dup of last
            int row = glist[idx];
            rowid_s[t] = row;
            srow_s[t] = np_sum256_sq(ze + (size_t)row * DD);
        }
        __syncthreads();

        // wave-uniform z-row pointers (scalar loads)
        const float* zp[16];
#pragma unroll
        for (int r = 0; r < 16; ++r)
            zp[r] = ze + (size_t)__builtin_amdgcn_readfirstlane(rowid_s[r]) * DD;

        // thread t emulates code k=t for all 16 rows: sequential 1-acc FMA over d
        float m32[16];
#pragma unroll
        for (int r = 0; r < 16; ++r) m32[r] = 0.f;
        for (int d4 = 0; d4 < 64; ++d4) {
            float4 e4 = e4p[d4];
            const int d = d4 * 4;
#pragma unroll
            for (int r = 0; r < 16; ++r) {
                m32[r] = __fmaf_rn(zp[r][d + 0], e4.x, m32[r]);
                m32[r] = __fmaf_rn(zp[r][d + 1], e4.y, m32[r]);
                m32[r] = __fmaf_rn(zp[r][d + 2], e4.z, m32[r]);
                m32[r] = __fmaf_rn(zp[r][d + 3], e4.w, m32[r]);
            }
        }
#pragma unroll
        for (int r = 0; r < 16; ++r) {
            float A = __fadd_rn(srow_s[r], se_k);
            dq[r][t] = __fsub_rn(A, __fmul_rn(2.0f, m32[r]));
        }
        __syncthreads();

        // per-row argmin: 16 threads per row (r = t>>4, portion p = t&15)
        {
            const int r = t >> 4, p = t & 15;
            float bv = 3.4e38f; int bk = 0x7fffffff;
#pragma unroll
            for (int i = 0; i < 16; ++i) {
                int k = p * 16 + i;
                float v = dq[r][k];
                if (v < bv) { bv = v; bk = k; }   // strict <: lowest index in subset
            }
#pragma unroll
            for (int off = 1; off < 16; off <<= 1) {
                float ov = __shfl_xor(bv, off, 64);
                int   ok = __shfl_xor(bk, off, 64);
                if (ov < bv || (ov == bv && ok < bk)) { bv = ov; bk = ok; }
            }
            if (p == 0 && g + r < F) out_inds[rowid_s[r]] = (float)bk;
        }
        __syncthreads();
    }
}

// ---------- gather: z_q[row] = emb[inds[row]] — pure streaming-write kernel ----------
__global__ __launch_bounds__(256)
void vq_gather(const float* __restrict__ emb, const float* __restrict__ out_inds,
               float* __restrict__ out_zq)
{
    const int t = threadIdx.x;
    const int w = t >> 6, l = t & 63;
    const size_t m0 = (size_t)blockIdx.x * 128 + (size_t)w * 32;
#pragma unroll 8
    for (int r = 0; r < 32; ++r) {
        int k = (int)out_inds[m0 + r];
        float4 v = *reinterpret_cast<const float4*>(emb + (size_t)k * DD + l * 4);
        *reinterpret_cast<float4*>(out_zq + (m0 + r) * DD + l * 4) = v;
    }
}

// ---------- finalize: loss = (1 + 0.25) * mean((z - q)^2) ----------
__global__ void vq_fin(const double* __restrict__ accum, float* __restrict__ out_loss) {
    *out_loss = (float)(1.25 * (*accum) / ((double)NROWS * (double)DD));
}

extern "C" void kernel_launch(void* const* d_in, const int* in_sizes, int n_in,
                              void* d_out, int out_size, void* d_ws, size_t ws_size,
                              hipStream_t stream) {
    const float* ze  = (const float*)d_in[0];
    const float* emb = (const float*)d_in[1];
    float* out      = (float*)d_out;
    float* out_zq   = out;
    float* out_inds = out + (size_t)NROWS * DD;
    float* out_loss = out + (size_t)NROWS * DD + NROWS;

    double* accum = (double*)d_ws;                                   // @0, 8B
    int*    gcnt  = (int*)((char*)d_ws + 8);                         // @8, 4B
    float*  se    = (float*)((char*)d_ws + 256);                     // @256, 1KB
    int*    glist = (int*)((char*)d_ws + 4096);                      // @4K, 256KB
    unsigned short* ph = (unsigned short*)((char*)d_ws + 4096 + 262144);  // 128KB

    vq_prep<<<1, 256, 0, stream>>>(emb, se, accum, gcnt);
    vq_split<<<KC * DD / (256 * 4), 256, 0, stream>>>(emb, ph);
    vq_main<<<NROWS / BM, 256, 0, stream>>>(ze, ph, se, out_inds, accum, glist, gcnt);
    vq_fix<<<1024, 256, 0, stream>>>(ze, emb, se, glist, gcnt, out_inds);
    vq_gather<<<NROWS / 128, 256, 0, stream>>>(emb, out_inds, out_zq);
    vq_fin<<<1, 1, 0, stream>>>(accum, out_loss);
}